// Round 7
// baseline (535.990 us; speedup 1.0000x reference)
//
#include <hip/hip_runtime.h>

// ESN recurrence, MI355X — 8 homogeneous waves, 2 slots/lane, inline u.
//
// THEORY LADDER: R1 615 cyc/step (1 consumer wave) -> R5 363 (4 waves,
// wave halo) -> R6 337 (DPP, bpermute was only ~13cy each). Cross-round
// fit: per-wave transcendental wave-ops cost ~25 cyc each (throughput or
// exposed exp2->add->rcp latency); 8 trans/step/wave ~= 200 of 337 cyc.
// THIS ROUND: halve per-wave trans again -> 2 slots/lane, ALL 8 waves run
// the recurrence. 32 rows x 16 lanes; row j owns window [16j-8,16j+24)
// (32 slots: core 16, halo 8/side; speed-of-light 1 slot/step => halo
// exchange every NTH=8 steps via S[par][512] + lgkm-only barrier).
// Producers and the 64KB ubuf are DELETED: x[b,t,:] is wave-uniform, so u
// is computed inline (16 fma/step/lane, hidden under trans latency; x
// loads broadcast from L1, 3-deep register prefetch). The two tanh chains
// per lane are batched to pipeline trans latency. u fma order and
// esn_step math are bitwise-identical to R1-R6 => absmax must remain
// exactly 0.00390625 (built-in correctness/theory check).
//
// Store: core lanes (p in [4,12)) write float2; a wave's 32 active lanes
// cover one contiguous 256B span per step. Barriers are lgkm-only so the
// output stores stay in flight.

#define B_DIM 128
#define T_DIM 1024
#define D_DIM 8
#define R_DIM 512
#define NTH   8             // steps between halo exchanges (= halo margin)

#define SC   2.8853900817779268f   // 2*log2(e), folded into W and betas
#define BP_S (0.15f * SC)          // coeff on s[r+1], scaled
#define BM_S (0.85f * SC)          // coeff on s[r-1], scaled

__device__ __forceinline__ float esn_step(float L, float R, float u) {
    // pre' = 2log2e * (0.85 L + 0.15 R + u_raw); u already scaled.
    const float pre = fmaf(BM_S, L, fmaf(BP_S, R, u));
#if __has_builtin(__builtin_amdgcn_exp2f) && __has_builtin(__builtin_amdgcn_rcpf)
    const float e = __builtin_amdgcn_exp2f(pre);
    return fmaf(-2.0f, __builtin_amdgcn_rcpf(e + 1.0f), 1.0f);
#else
    const float e = exp2f(pre);
    return 1.0f - 2.0f / (e + 1.0f);
#endif
}

// DPP row shifts within 16-lane rows; bound_ctrl=1 -> row-edge lanes read
// 0.0f (they are window edges = decayed halo, bounded garbage is fine).
__device__ __forceinline__ float dpp_prev(float v) {   // lane i <- lane i-1
    return __uint_as_float((unsigned)__builtin_amdgcn_update_dpp(
        0, (int)__float_as_uint(v), 0x111, 0xf, 0xf, true));
}
__device__ __forceinline__ float dpp_next(float v) {   // lane i <- lane i+1
    return __uint_as_float((unsigned)__builtin_amdgcn_update_dpp(
        0, (int)__float_as_uint(v), 0x101, 0xf, 0xf, true));
}

__device__ __forceinline__ void barrier_lds_only() {
    // LDS drain + barrier WITHOUT vmcnt(0): pending global stores stay in
    // flight across the barrier.
    asm volatile("s_waitcnt lgkmcnt(0)\n\ts_barrier" ::: "memory");
}

__global__ __launch_bounds__(512, 1) void esn_kernel(const float* __restrict__ x,
                                                     const float* __restrict__ W,
                                                     float* __restrict__ out) {
    __shared__ float S[2][R_DIM];   // halo-exchange state, parity dbuf, 4 KB

    const int b   = blockIdx.x;
    const int tid = threadIdx.x;
    const float* xb = x + (size_t)b * T_DIM * D_DIM;

    const int j  = tid >> 4;                         // row 0..31
    const int p  = tid & 15;                         // lane within row
    const int r0 = (16 * j - 8 + 2 * p) & (R_DIM - 1);  // even; r0+1 <= 511
    const bool core = (p >= 4) && (p < 12);

    // ---- W rows r0, r0+1 (scaled) in registers.
    const float4 A0 = *(const float4*)(W + r0 * D_DIM);
    const float4 A1 = *(const float4*)(W + r0 * D_DIM + 4);
    const float4 B0 = *(const float4*)(W + (r0 + 1) * D_DIM);
    const float4 B1 = *(const float4*)(W + (r0 + 1) * D_DIM + 4);
    const float a0 = A0.x * SC, a1 = A0.y * SC, a2 = A0.z * SC, a3 = A0.w * SC;
    const float a4 = A1.x * SC, a5 = A1.y * SC, a6 = A1.z * SC, a7 = A1.w * SC;
    const float c0 = B0.x * SC, c1 = B0.y * SC, c2 = B0.z * SC, c3 = B0.w * SC;
    const float c4 = B1.x * SC, c5 = B1.y * SC, c6 = B1.z * SC, c7 = B1.w * SC;

    float s0 = 0.0f, s1 = 0.0f;                      // zeros incl. halo (exact)
    float* op = out + (size_t)b * T_DIM * R_DIM + r0;

    // ---- x register pipeline: step i uses x[i+1]; prefetch x[i+3].
    float4 xa0 = *(const float4*)(xb + D_DIM);
    float4 xc0 = *(const float4*)(xb + D_DIM + 4);
    float4 xa1 = *(const float4*)(xb + 2 * D_DIM);
    float4 xc1 = *(const float4*)(xb + 2 * D_DIM + 4);

    int par = 0;
    for (int i = 0; i < T_DIM - 1; ++i) {
        // prefetch x for step i+2 (wave-uniform address -> L1 broadcast)
        int tp = i + 3; if (tp > T_DIM - 1) tp = T_DIM - 1;
        const float4 pa = *(const float4*)(xb + tp * D_DIM);
        const float4 pc = *(const float4*)(xb + tp * D_DIM + 4);

        // inline u for this step (same fma order as producers in R1-R6)
        float u0 = xa0.x * a0;
        u0 = fmaf(xa0.y, a1, u0); u0 = fmaf(xa0.z, a2, u0);
        u0 = fmaf(xa0.w, a3, u0); u0 = fmaf(xc0.x, a4, u0);
        u0 = fmaf(xc0.y, a5, u0); u0 = fmaf(xc0.z, a6, u0);
        u0 = fmaf(xc0.w, a7, u0);
        float u1 = xa0.x * c0;
        u1 = fmaf(xa0.y, c1, u1); u1 = fmaf(xa0.z, c2, u1);
        u1 = fmaf(xa0.w, c3, u1); u1 = fmaf(xc0.x, c4, u1);
        u1 = fmaf(xc0.y, c5, u1); u1 = fmaf(xc0.z, c6, u1);
        u1 = fmaf(xc0.w, c7, u1);

        // neighbor exchange on the VALU pipe (no LDS)
        const float Lh = dpp_prev(s1);   // s[r0-1] (left lane's slot1)
        const float Rh = dpp_next(s0);   // s[r0+2] (right lane's slot0)

        // two tanh chains, batched back-to-back so trans latency pipelines
        const float n0 = esn_step(Lh, s1, u0);
        const float n1 = esn_step(s0, Rh, u1);

        if (core) *(float2*)op = make_float2(n0, n1);
        op += R_DIM;
        s0 = n0; s1 = n1;
        xa0 = xa1; xc0 = xc1; xa1 = pa; xc1 = pc;

        // halo exchange every NTH steps (margin exactly covers NTH)
        if ((i & (NTH - 1)) == (NTH - 1)) {
            if (core) *(float2*)&S[par][r0] = make_float2(s0, s1);
            barrier_lds_only();
            const float2 sv = *(const float2*)&S[par][r0];
            s0 = sv.x; s1 = sv.y;
            par ^= 1;
        }
    }

    // Reference's final timestep is all zeros (d_out is poisoned 0xAA).
    out[(size_t)b * T_DIM * R_DIM + (size_t)(T_DIM - 1) * R_DIM + tid] = 0.0f;
}

extern "C" void kernel_launch(void* const* d_in, const int* in_sizes, int n_in,
                              void* d_out, int out_size, void* d_ws, size_t ws_size,
                              hipStream_t stream) {
    const float* x = (const float*)d_in[0];   // [B, T, D] fp32
    const float* W = (const float*)d_in[1];   // [R, D] fp32
    float* out = (float*)d_out;               // [B, T, R] fp32

    esn_kernel<<<dim3(B_DIM), dim3(512), 0, stream>>>(x, W, out);
}